// Round 11
// baseline (319.724 us; speedup 1.0000x reference)
//
#include <hip/hip_runtime.h>
#include <hip/hip_bf16.h>

#define H 128
#define BSH 8              // 256 nodes per coarse bucket
#define MAXB 1024          // max buckets
#define PCH 4096           // edges per partition/hist block
#define PIT (PCH / 256)
#define IBCAP 1536         // per-quarter LDS bin capacity (mean 768, >25 sigma)

typedef __attribute__((ext_vector_type(8))) short short8;
typedef __attribute__((ext_vector_type(4))) short short4v;
typedef __attribute__((ext_vector_type(4))) float floatx4;
typedef unsigned short ushort_t;
typedef unsigned int uint_t;

__device__ __forceinline__ short f2bf(float f) {
    __hip_bfloat16 h = __float2bfloat16(f);
    return *reinterpret_cast<short*>(&h);
}
__device__ __forceinline__ float bflo(uint_t u) { return __uint_as_float(u << 16); }
__device__ __forceinline__ float bfhi(uint_t u) { return __uint_as_float(u & 0xFFFF0000u); }
__device__ __forceinline__ uint_t pack_bf2(float x, float y) {
    return (uint_t)(ushort_t)f2bf(x) | ((uint_t)(ushort_t)f2bf(y) << 16);
}
__device__ __forceinline__ void acc8(float* acc, uint4 r) {
    acc[0] += bflo(r.x); acc[1] += bfhi(r.x);
    acc[2] += bflo(r.y); acc[3] += bfhi(r.y);
    acc[4] += bflo(r.z); acc[5] += bfhi(r.z);
    acc[6] += bflo(r.w); acc[7] += bfhi(r.w);
}

// ===========================================================================
// Coarse bucket histogram (LDS) + fused fp32->bf16 converts (emb + weights).
// NF argument is the PADDED flag count (multiple of 256) so buckets are
// type-pure and align 1:1 with groups of 4 sage5 blocks.
// ===========================================================================
__global__ __launch_bounds__(256)
void bucket_hist_cvt_kernel(const int* __restrict__ ei1, const int* __restrict__ ei2,
                            int E, int NF, int B, int* __restrict__ bcnt, int nbh,
                            const float* __restrict__ a, int n4a,
                            const float* __restrict__ b, int n4b,
                            ushort_t* __restrict__ da, ushort_t* __restrict__ db,
                            const float* __restrict__ Wl_cf, const float* __restrict__ Wr_cf,
                            const float* __restrict__ Wl_fc, const float* __restrict__ Wr_fc,
                            const float* __restrict__ W1, ushort_t* __restrict__ wb) {
    __shared__ int h[MAXB];
    int tid = threadIdx.x;
    if ((int)blockIdx.x < nbh) {
        for (int i = tid; i < B; i += 256) h[i] = 0;
        __syncthreads();
        int base = blockIdx.x * PCH;
        #pragma unroll 4
        for (int it = 0; it < PIT; ++it) {
            int t = base + it * 256 + tid;
            if (t < 2 * E) {
                int g = (t < E) ? ei1[E + t] : (ei2[E + t - E] + NF);
                atomicAdd(&h[g >> BSH], 1);
            }
        }
        __syncthreads();
        for (int i = tid; i < B; i += 256)
            if (h[i]) atomicAdd(&bcnt[i], h[i]);
        return;
    }
    // ---- cvt part ----
    int i = ((int)blockIdx.x - nbh) * 256 + tid;
    const float* src; ushort_t* dst; int k;
    if (i < n4a) { src = a; dst = da; k = i; }
    else if (i < n4a + n4b) { src = b; dst = db; k = i - n4a; }
    else {
        int idx = (i - n4a - n4b) * 4;
        if (idx >= 98304) return;
        int off;
        if      (idx < 16384) { src = Wl_cf; off = idx; }
        else if (idx < 32768) { src = Wr_cf; off = idx - 16384; }
        else if (idx < 49152) { src = Wl_fc; off = idx - 32768; }
        else if (idx < 65536) { src = Wr_fc; off = idx - 49152; }
        else                  { src = W1;    off = idx - 65536; }
        float4 v = *(const float4*)(src + off);
        short4v s;
        s[0] = f2bf(v.x); s[1] = f2bf(v.y); s[2] = f2bf(v.z); s[3] = f2bf(v.w);
        *(short4v*)(wb + idx) = s;
        return;
    }
    float4 v = ((const float4*)src)[k];
    short4v s;
    s[0] = f2bf(v.x); s[1] = f2bf(v.y); s[2] = f2bf(v.z); s[3] = f2bf(v.w);
    ((short4v*)dst)[k] = s;
}

// ===========================================================================
// Partition, single-pass-rank (NF = padded flag count).
// ===========================================================================
__global__ __launch_bounds__(256)
void partition_kernel(const int* __restrict__ ei1, const int* __restrict__ ei2,
                      int E, int NF, int B, const int* __restrict__ bcnt,
                      int* __restrict__ bfront, uint_t* __restrict__ part) {
    __shared__ int h[MAXB];
    __shared__ int basex[MAXB];
    __shared__ int sdata[256];
    int tid = threadIdx.x;
    // local exclusive scan of bcnt -> basex (global bucket bases)
    {
        int base4 = tid * 4;
        int v[4]; int s = 0;
        #pragma unroll
        for (int i = 0; i < 4; ++i) { int idx = base4 + i; v[i] = (idx < B) ? bcnt[idx] : 0; s += v[i]; }
        sdata[tid] = s;
        __syncthreads();
        for (int off = 1; off < 256; off <<= 1) {
            int t = (tid >= off) ? sdata[tid - off] : 0;
            __syncthreads();
            sdata[tid] += t;
            __syncthreads();
        }
        int excl = tid ? sdata[tid - 1] : 0;
        #pragma unroll
        for (int i = 0; i < 4; ++i) {
            int idx = base4 + i;
            if (idx < B) basex[idx] = excl;
            excl += v[i];
        }
    }
    for (int i = tid; i < B; i += 256) h[i] = 0;
    __syncthreads();

    int base = blockIdx.x * PCH;
    int pay[PIT]; int bkv[PIT]; int rv[PIT];
    #pragma unroll
    for (int it = 0; it < PIT; ++it) {
        int t = base + it * 256 + tid;
        bkv[it] = -1;
        if (t < 2 * E) {
            int g, s;
            if (t < E) { g = ei1[E + t]; s = ei1[t]; }
            else       { int e = t - E; g = ei2[E + e] + NF; s = ei2[e]; }
            int bk = g >> BSH;
            bkv[it] = bk;
            rv[it] = atomicAdd(&h[bk], 1);
            pay[it] = (int)(((uint_t)(g & 255) << 24) | (uint_t)s);
        }
    }
    __syncthreads();
    for (int i = tid; i < B; i += 256) {
        int c = h[i];
        if (c) basex[i] += atomicAdd(&bfront[i], c);   // reserve block's range
    }
    __syncthreads();
    #pragma unroll
    for (int it = 0; it < PIT; ++it) {
        if (bkv[it] >= 0)
            part[basex[bkv[it]] + rv[it]] = (uint_t)pay[it];
    }
}

// ===========================================================================
// FUSED in-LDS fine-bin + gather-mean + MFMA SAGE (sage5).
// Block = 64 rows = quarter q of bucket bkt (buckets are type-pure via NFP).
//   1) seg bounds from bcnt reduction; 2) LDS bin the quarter's edges
//      (hist64 + wave scan + scatter into ibins); 3) 16-lane-group gather,
//      2 rows interleaved, indices from LDS; 4) MFMA Wl / self-emb / Wr /
//      relu+bias / W1-part as before. No global offs/bins at all.
// ===========================================================================
__global__ __launch_bounds__(256)
void sage5_kernel(int nbF, int NF, int NC, int NFB,
                  const int* __restrict__ bcnt, const uint_t* __restrict__ part,
                  ushort_t* __restrict__ outf, const ushort_t* __restrict__ embf,
                  ushort_t* __restrict__ outc, const ushort_t* __restrict__ embc,
                  const ushort_t* __restrict__ wlf, const ushort_t* __restrict__ wrf,
                  const float* __restrict__ blf,
                  const ushort_t* __restrict__ wlc, const ushort_t* __restrict__ wrc,
                  const float* __restrict__ blc,
                  const ushort_t* __restrict__ W1) {
    __shared__ short A[64][136];              // 17408 B
    __shared__ int ibins[IBCAP];              // 6144 B
    __shared__ int cnt[64];
    __shared__ int excl[65];
    __shared__ int sdata[256];
    bool isF = (int)blockIdx.x < nbF;
    int blk = isF ? (int)blockIdx.x : (int)blockIdx.x - nbF;
    int nrows = isF ? NF : NC;
    int rbase = blk * 64;
    int bkt = isF ? (blk >> 2) : (NFB + (blk >> 2));
    int q = blk & 3;
    ushort_t* io = isF ? outf : outc;         // write-only output
    const ushort_t* embS = isF ? embf : embc; // self rows
    const ushort_t* embN = isF ? embc : embf; // neighbor source rows
    const ushort_t* Wl = isF ? wlf : wlc;
    const ushort_t* Wr = isF ? wrf : wrc;
    const float* bl = isF ? blf : blc;
    int koff = isF ? 128 : 0;

    int tid = threadIdx.x;
    int lane = tid & 63;
    int wv = tid >> 6;
    int l15 = lane & 15;
    int quad = lane >> 4;
    int nb0 = 32 * wv + l15;

    float blv0 = bl[nb0];
    float blv1 = bl[nb0 + 16];

    // ---- seg bounds: seg0 = sum bcnt[0..bkt) ----
    {
        int partial = 0;
        for (int i = tid; i < bkt; i += 256) partial += bcnt[i];
        sdata[tid] = partial;
        __syncthreads();
        for (int off = 128; off > 0; off >>= 1) {
            if (tid < off) sdata[tid] += sdata[tid + off];
            __syncthreads();
        }
    }
    int seg0 = sdata[0];
    int seg1 = seg0 + bcnt[bkt];

    // ---- in-LDS fine bin of this quarter ----
    if (tid < 64) cnt[tid] = 0;
    __syncthreads();
    for (int k = seg0 + tid; k < seg1; k += 256) {
        int l = (int)(part[k] >> 24);
        if ((l >> 6) == q) atomicAdd(&cnt[l & 63], 1);
    }
    __syncthreads();
    if (tid < 64) {
        int v = cnt[tid];
        int inc = v;
        #pragma unroll
        for (int off = 1; off < 64; off <<= 1) {
            int t = __shfl_up(inc, off, 64);
            if (tid >= off) inc += t;
        }
        excl[tid] = inc - v;
        if (tid == 63) excl[64] = inc;
        cnt[tid] = 0;
    }
    __syncthreads();
    for (int k = seg0 + tid; k < seg1; k += 256) {
        uint_t e = part[k];
        int l = (int)(e >> 24);
        if ((l >> 6) == q) {
            int l6 = l & 63;
            int r = atomicAdd(&cnt[l6], 1);
            int pos = excl[l6] + r;
            if (pos < IBCAP) ibins[pos] = (int)(e & 0x00FFFFFFu);
        }
    }
    __syncthreads();

    // ---- gather means into A[:,0:128), 2 rows per 16-lane group ----
    {
        const ushort_t* epN = embN + l15 * 8;
        #pragma unroll
        for (int half = 0; half < 2; ++half) {
            int r0 = wv * 16 + half * 8 + quad;   // row pair (r0, r0+4)
            int r1 = r0 + 4;
            int st0 = excl[r0], d0 = excl[r0 + 1] - excl[r0];
            int st1 = excl[r1], d1 = excl[r1 + 1] - excl[r1];

            float a0[8], a1[8];
            #pragma unroll
            for (int t = 0; t < 8; ++t) { a0[t] = 0.f; a1[t] = 0.f; }

            int dmax = d0 > d1 ? d0 : d1;
            for (int k = 0; k < dmax; k += 2) {
                bool b00 = k < d0, b01 = (k + 1) < d0;
                bool b10 = k < d1, b11 = (k + 1) < d1;
                int s00 = b00 ? ibins[st0 + k]     : 0;
                int s01 = b01 ? ibins[st0 + k + 1] : 0;
                int s10 = b10 ? ibins[st1 + k]     : 0;
                int s11 = b11 ? ibins[st1 + k + 1] : 0;
                uint4 q00, q01, q10, q11;
                if (b00) q00 = *(const uint4*)(epN + (size_t)s00 * H);
                if (b10) q10 = *(const uint4*)(epN + (size_t)s10 * H);
                if (b01) q01 = *(const uint4*)(epN + (size_t)s01 * H);
                if (b11) q11 = *(const uint4*)(epN + (size_t)s11 * H);
                if (b00) acc8(a0, q00);
                if (b10) acc8(a1, q10);
                if (b01) acc8(a0, q01);
                if (b11) acc8(a1, q11);
            }

            float inv0 = 1.0f / fmaxf((float)d0, 1.0f);
            float inv1 = 1.0f / fmaxf((float)d1, 1.0f);
            uint4 o0, o1;
            o0.x = pack_bf2(a0[0] * inv0, a0[1] * inv0);
            o0.y = pack_bf2(a0[2] * inv0, a0[3] * inv0);
            o0.z = pack_bf2(a0[4] * inv0, a0[5] * inv0);
            o0.w = pack_bf2(a0[6] * inv0, a0[7] * inv0);
            o1.x = pack_bf2(a1[0] * inv1, a1[1] * inv1);
            o1.y = pack_bf2(a1[2] * inv1, a1[3] * inv1);
            o1.z = pack_bf2(a1[4] * inv1, a1[5] * inv1);
            o1.w = pack_bf2(a1[6] * inv1, a1[7] * inv1);
            *(uint4*)&A[r0][l15 * 8] = o0;
            *(uint4*)&A[r1][l15 * 8] = o1;
        }
    }

    floatx4 acc[4][2];
    #pragma unroll
    for (int i = 0; i < 4; ++i)
        #pragma unroll
        for (int j = 0; j < 2; ++j)
            acc[i][j] = (floatx4){0.f, 0.f, 0.f, 0.f};

    __syncthreads();
    #pragma unroll
    for (int ks = 0; ks < 4; ++ks) {
        int kb = ks * 32 + quad * 8;
        short8 b0 = *(const short8*)(Wl + (size_t)nb0 * H + kb);
        short8 b1 = *(const short8*)(Wl + (size_t)(nb0 + 16) * H + kb);
        #pragma unroll
        for (int mt = 0; mt < 4; ++mt) {
            short8 a = *(const short8*)&A[16 * mt + l15][kb];
            acc[mt][0] = __builtin_amdgcn_mfma_f32_16x16x32_bf16(a, b0, acc[mt][0], 0, 0, 0);
            acc[mt][1] = __builtin_amdgcn_mfma_f32_16x16x32_bf16(a, b1, acc[mt][1], 0, 0, 0);
        }
    }
    __syncthreads();

    // ---- stage self-emb rows into same buffer ----
    #pragma unroll
    for (int j = 0; j < 4; ++j) {
        int idx = tid + 256 * j;
        int r = idx >> 4, c = idx & 15;
        int row = rbase + r;
        uint4 v = (uint4){0u, 0u, 0u, 0u};
        if (row < nrows) v = *(const uint4*)(embS + (size_t)row * H + c * 8);
        *(uint4*)&A[r][c * 8] = v;
    }
    __syncthreads();
    #pragma unroll
    for (int ks = 0; ks < 4; ++ks) {
        int kb = ks * 32 + quad * 8;
        short8 b0 = *(const short8*)(Wr + (size_t)nb0 * H + kb);
        short8 b1 = *(const short8*)(Wr + (size_t)(nb0 + 16) * H + kb);
        #pragma unroll
        for (int mt = 0; mt < 4; ++mt) {
            short8 a = *(const short8*)&A[16 * mt + l15][kb];
            acc[mt][0] = __builtin_amdgcn_mfma_f32_16x16x32_bf16(a, b0, acc[mt][0], 0, 0, 0);
            acc[mt][1] = __builtin_amdgcn_mfma_f32_16x16x32_bf16(a, b1, acc[mt][1], 0, 0, 0);
        }
    }
    __syncthreads();

    // ---- epilogue: relu+bias -> A[64][0:128) ----
    #pragma unroll
    for (int mt = 0; mt < 4; ++mt)
        #pragma unroll
        for (int nt = 0; nt < 2; ++nt) {
            float blv = nt ? blv1 : blv0;
            int colw = nb0 + 16 * nt;
            #pragma unroll
            for (int rg = 0; rg < 4; ++rg) {
                int row = 16 * mt + quad * 4 + rg;
                A[row][colw] = f2bf(fmaxf(acc[mt][nt][rg] + blv, 0.0f));
                acc[mt][nt][rg] = 0.0f;
            }
        }
    __syncthreads();

    // ---- W1-part GEMM ----
    const ushort_t* W1p = W1 + koff;
    #pragma unroll
    for (int ks = 0; ks < 4; ++ks) {
        int kb = ks * 32 + quad * 8;
        short8 b0 = *(const short8*)(W1p + (size_t)nb0 * 256 + kb);
        short8 b1 = *(const short8*)(W1p + (size_t)(nb0 + 16) * 256 + kb);
        #pragma unroll
        for (int mt = 0; mt < 4; ++mt) {
            short8 a = *(const short8*)&A[16 * mt + l15][kb];
            acc[mt][0] = __builtin_amdgcn_mfma_f32_16x16x32_bf16(a, b0, acc[mt][0], 0, 0, 0);
            acc[mt][1] = __builtin_amdgcn_mfma_f32_16x16x32_bf16(a, b1, acc[mt][1], 0, 0, 0);
        }
    }

    #pragma unroll
    for (int mt = 0; mt < 4; ++mt)
        #pragma unroll
        for (int rg = 0; rg < 4; ++rg) {
            int row = rbase + 16 * mt + quad * 4 + rg;
            if (row < nrows) {
                io[(size_t)row * H + nb0]      = (ushort_t)f2bf(acc[mt][0][rg]);
                io[(size_t)row * H + nb0 + 16] = (ushort_t)f2bf(acc[mt][1][rg]);
            }
        }
}

// ===========================================================================
// Fallback fused kernel (global offs/bins CSR) — only if ws too small / B big.
// ===========================================================================
__global__ __launch_bounds__(256)
void sage4_kernel(int nbF, int NF, int NC,
                  const int* __restrict__ offs, const int* __restrict__ bins,
                  ushort_t* __restrict__ outf, const ushort_t* __restrict__ embf,
                  ushort_t* __restrict__ outc, const ushort_t* __restrict__ embc,
                  const ushort_t* __restrict__ wlf, const ushort_t* __restrict__ wrf,
                  const float* __restrict__ blf,
                  const ushort_t* __restrict__ wlc, const ushort_t* __restrict__ wrc,
                  const float* __restrict__ blc,
                  const ushort_t* __restrict__ W1) {
    __shared__ short A[64][136];
    bool isF = (int)blockIdx.x < nbF;
    int nrows = isF ? NF : NC;
    int rbase = (isF ? blockIdx.x : blockIdx.x - nbF) * 64;
    ushort_t* io = isF ? outf : outc;
    const ushort_t* embS = isF ? embf : embc;
    const ushort_t* embN = isF ? embc : embf;
    const ushort_t* Wl = isF ? wlf : wlc;
    const ushort_t* Wr = isF ? wrf : wrc;
    const float* bl = isF ? blf : blc;
    int koff = isF ? 128 : 0;
    int gofs = isF ? 0 : NF;

    int tid = threadIdx.x;
    int lane = tid & 63;
    int wv = tid >> 6;
    int l15 = lane & 15;
    int quad = lane >> 4;
    int nb0 = 32 * wv + l15;

    float blv0 = bl[nb0];
    float blv1 = bl[nb0 + 16];

    {
        const ushort_t* epN = embN + l15 * 8;
        #pragma unroll
        for (int half = 0; half < 2; ++half) {
            int r0 = wv * 16 + half * 8 + quad;
            int r1 = r0 + 4;
            int row0 = rbase + r0, row1 = rbase + r1;
            int st0 = 0, en0 = 0, st1 = 0, en1 = 0;
            if (row0 < nrows) { int g = gofs + row0; st0 = offs[g]; en0 = offs[g + 1]; }
            if (row1 < nrows) { int g = gofs + row1; st1 = offs[g]; en1 = offs[g + 1]; }
            int d0 = en0 - st0, d1 = en1 - st1;
            int n0 = d0 < 16 ? d0 : 16;
            int n1 = d1 < 16 ? d1 : 16;
            int pre0 = (l15 < n0) ? bins[st0 + l15] : 0;
            int pre1 = (l15 < n1) ? bins[st1 + l15] : 0;

            float a0[8], a1[8];
            #pragma unroll
            for (int t = 0; t < 8; ++t) { a0[t] = 0.f; a1[t] = 0.f; }

            int nmax = n0 > n1 ? n0 : n1;
            for (int k = 0; k < nmax; k += 2) {
                int s00 = __shfl(pre0, k,     16);
                int s01 = __shfl(pre0, k + 1, 16);
                int s10 = __shfl(pre1, k,     16);
                int s11 = __shfl(pre1, k + 1, 16);
                bool b00 = k < n0, b01 = (k + 1) < n0;
                bool b10 = k < n1, b11 = (k + 1) < n1;
                uint4 q00, q01, q10, q11;
                if (b00) q00 = *(const uint4*)(epN + (size_t)s00 * H);
                if (b10) q10 = *(const uint4*)(epN + (size_t)s10 * H);
                if (b01) q01 = *(const uint4*)(epN + (size_t)s01 * H);
                if (b11) q11 = *(const uint4*)(epN + (size_t)s11 * H);
                if (b00) acc8(a0, q00);
                if (b10) acc8(a1, q10);
                if (b01) acc8(a0, q01);
                if (b11) acc8(a1, q11);
            }
            for (int kk = st0 + 16; kk < en0; ++kk) {
                int s = bins[kk];
                uint4 rr = *(const uint4*)(epN + (size_t)s * H);
                acc8(a0, rr);
            }
            for (int kk = st1 + 16; kk < en1; ++kk) {
                int s = bins[kk];
                uint4 rr = *(const uint4*)(epN + (size_t)s * H);
                acc8(a1, rr);
            }

            float inv0 = 1.0f / fmaxf((float)d0, 1.0f);
            float inv1 = 1.0f / fmaxf((float)d1, 1.0f);
            uint4 o0, o1;
            o0.x = pack_bf2(a0[0] * inv0, a0[1] * inv0);
            o0.y = pack_bf2(a0[2] * inv0, a0[3] * inv0);
            o0.z = pack_bf2(a0[4] * inv0, a0[5] * inv0);
            o0.w = pack_bf2(a0[6] * inv0, a0[7] * inv0);
            o1.x = pack_bf2(a1[0] * inv1, a1[1] * inv1);
            o1.y = pack_bf2(a1[2] * inv1, a1[3] * inv1);
            o1.z = pack_bf2(a1[4] * inv1, a1[5] * inv1);
            o1.w = pack_bf2(a1[6] * inv1, a1[7] * inv1);
            *(uint4*)&A[r0][l15 * 8] = o0;
            *(uint4*)&A[r1][l15 * 8] = o1;
        }
    }

    floatx4 acc[4][2];
    #pragma unroll
    for (int i = 0; i < 4; ++i)
        #pragma unroll
        for (int j = 0; j < 2; ++j)
            acc[i][j] = (floatx4){0.f, 0.f, 0.f, 0.f};

    __syncthreads();
    #pragma unroll
    for (int ks = 0; ks < 4; ++ks) {
        int kb = ks * 32 + quad * 8;
        short8 b0 = *(const short8*)(Wl + (size_t)nb0 * H + kb);
        short8 b1 = *(const short8*)(Wl + (size_t)(nb0 + 16) * H + kb);
        #pragma unroll
        for (int mt = 0; mt < 4; ++mt) {
            short8 a = *(const short8*)&A[16 * mt + l15][kb];
            acc[mt][0] = __builtin_amdgcn_mfma_f32_16x16x32_bf16(a, b0, acc[mt][0], 0, 0, 0);
            acc[mt][1] = __builtin_amdgcn_mfma_f32_16x16x32_bf16(a, b1, acc[mt][1], 0, 0, 0);
        }
    }
    __syncthreads();

    #pragma unroll
    for (int j = 0; j < 4; ++j) {
        int idx = tid + 256 * j;
        int r = idx >> 4, c = idx & 15;
        int row = rbase + r;
        uint4 v = (uint4){0u, 0u, 0u, 0u};
        if (row < nrows) v = *(const uint4*)(embS + (size_t)row * H + c * 8);
        *(uint4*)&A[r][c * 8] = v;
    }
    __syncthreads();
    #pragma unroll
    for (int ks = 0; ks < 4; ++ks) {
        int kb = ks * 32 + quad * 8;
        short8 b0 = *(const short8*)(Wr + (size_t)nb0 * H + kb);
        short8 b1 = *(const short8*)(Wr + (size_t)(nb0 + 16) * H + kb);
        #pragma unroll
        for (int mt = 0; mt < 4; ++mt) {
            short8 a = *(const short8*)&A[16 * mt + l15][kb];
            acc[mt][0] = __builtin_amdgcn_mfma_f32_16x16x32_bf16(a, b0, acc[mt][0], 0, 0, 0);
            acc[mt][1] = __builtin_amdgcn_mfma_f32_16x16x32_bf16(a, b1, acc[mt][1], 0, 0, 0);
        }
    }
    __syncthreads();

    #pragma unroll
    for (int mt = 0; mt < 4; ++mt)
        #pragma unroll
        for (int nt = 0; nt < 2; ++nt) {
            float blv = nt ? blv1 : blv0;
            int colw = nb0 + 16 * nt;
            #pragma unroll
            for (int rg = 0; rg < 4; ++rg) {
                int row = 16 * mt + quad * 4 + rg;
                A[row][colw] = f2bf(fmaxf(acc[mt][nt][rg] + blv, 0.0f));
                acc[mt][nt][rg] = 0.0f;
            }
        }
    __syncthreads();

    const ushort_t* W1p = W1 + koff;
    #pragma unroll
    for (int ks = 0; ks < 4; ++ks) {
        int kb = ks * 32 + quad * 8;
        short8 b0 = *(const short8*)(W1p + (size_t)nb0 * 256 + kb);
        short8 b1 = *(const short8*)(W1p + (size_t)(nb0 + 16) * 256 + kb);
        #pragma unroll
        for (int mt = 0; mt < 4; ++mt) {
            short8 a = *(const short8*)&A[16 * mt + l15][kb];
            acc[mt][0] = __builtin_amdgcn_mfma_f32_16x16x32_bf16(a, b0, acc[mt][0], 0, 0, 0);
            acc[mt][1] = __builtin_amdgcn_mfma_f32_16x16x32_bf16(a, b1, acc[mt][1], 0, 0, 0);
        }
    }

    #pragma unroll
    for (int mt = 0; mt < 4; ++mt)
        #pragma unroll
        for (int rg = 0; rg < 4; ++rg) {
            int row = rbase + 16 * mt + quad * 4 + rg;
            if (row < nrows) {
                io[(size_t)row * H + nb0]      = (ushort_t)f2bf(acc[mt][0][rg]);
                io[(size_t)row * H + nb0 + 16] = (ushort_t)f2bf(acc[mt][1][rg]);
            }
        }
}

// ===========================================================================
// Fallback CSR kernels (scattered bin2 path) — only if ws too small.
// ===========================================================================
__global__ __launch_bounds__(256)
void hist2_kernel(const int* __restrict__ ei1, const int* __restrict__ ei2, int E,
                  int* __restrict__ deg1, int* __restrict__ deg2) {
    int t = blockIdx.x * 256 + threadIdx.x;
    if (t < E) atomicAdd(&deg1[ei1[E + t]], 1);
    else if (t < 2 * E) { int e = t - E; atomicAdd(&deg2[ei2[E + e]], 1); }
}

__global__ __launch_bounds__(256)
void scan_blocksum_kernel(const int* __restrict__ deg, int n, int* __restrict__ bsums) {
    __shared__ int sdata[256];
    int tid = threadIdx.x;
    int base = blockIdx.x * 1024 + tid * 4;
    int v = 0;
    #pragma unroll
    for (int i = 0; i < 4; ++i) { int idx = base + i; if (idx < n) v += deg[idx]; }
    sdata[tid] = v;
    __syncthreads();
    for (int off = 128; off > 0; off >>= 1) {
        if (tid < off) sdata[tid] += sdata[tid + off];
        __syncthreads();
    }
    if (tid == 0) bsums[blockIdx.x] = sdata[0];
}

__global__ __launch_bounds__(256)
void scan_write_kernel(int* __restrict__ data, int n, const int* __restrict__ bsums) {
    __shared__ int sdata[256];
    __shared__ int boff;
    int tid = threadIdx.x;
    if (tid < 64) {
        int acc = 0;
        for (int i = tid; i < (int)blockIdx.x; i += 64) acc += bsums[i];
        #pragma unroll
        for (int off = 32; off > 0; off >>= 1) acc += __shfl_xor(acc, off, 64);
        if (tid == 0) boff = acc;
    }
    int base = blockIdx.x * 1024 + tid * 4;
    int v[4]; int s = 0;
    #pragma unroll
    for (int i = 0; i < 4; ++i) { int idx = base + i; v[i] = (idx < n) ? data[idx] : 0; s += v[i]; }
    sdata[tid] = s;
    __syncthreads();
    for (int off = 1; off < 256; off <<= 1) {
        int t = (tid >= off) ? sdata[tid - off] : 0;
        __syncthreads();
        sdata[tid] += t;
        __syncthreads();
    }
    int excl = (tid == 0 ? 0 : sdata[tid - 1]) + boff;
    #pragma unroll
    for (int i = 0; i < 4; ++i) {
        int idx = base + i;
        if (idx < n) data[idx] = excl;
        excl += v[i];
    }
}

__global__ __launch_bounds__(256)
void incl_to_start_kernel(const int* __restrict__ incl, int nTot, int* __restrict__ offs) {
    int g = blockIdx.x * 256 + threadIdx.x;
    if (g < nTot) offs[g + 1] = incl[g];
    if (g == 0) offs[0] = 0;
}

__global__ __launch_bounds__(256)
void bin2_kernel(const int* __restrict__ ei1, const int* __restrict__ ei2, int E,
                 int* __restrict__ offs1, int* __restrict__ offs2,
                 int* __restrict__ bins) {
    int t = blockIdx.x * 256 + threadIdx.x;
    if (t < E) {
        int pos = atomicAdd(&offs1[ei1[E + t]], 1);
        bins[pos] = ei1[t];
    } else if (t < 2 * E) {
        int e = t - E;
        int pos = atomicAdd(&offs2[ei2[E + e]], 1);
        bins[pos] = ei2[e];
    }
}

// ===========================================================================
// Classifier: 16 lanes per pair (4 pairs/wave).
// ===========================================================================
__global__ __launch_bounds__(256)
void classify_kernel(const int* __restrict__ eli, int L,
                     const ushort_t* __restrict__ u_can,
                     const ushort_t* __restrict__ u_flag,
                     const float* __restrict__ b1,
                     const float* __restrict__ W2,
                     const float* __restrict__ b2,
                     float* __restrict__ out) {
    int tid = threadIdx.x;
    int lane = tid & 63;
    int wv = tid >> 6;
    int sub = lane >> 4;
    int l15 = lane & 15;
    int p = blockIdx.x * 16 + wv * 4 + sub;
    if (p >= L) return;
    int i = eli[p];
    int j = eli[L + p];
    uint4 a = ((const uint4*)(u_can  + (size_t)i * H))[l15];
    uint4 b = ((const uint4*)(u_flag + (size_t)j * H))[l15];
    float4 bb0 = ((const float4*)b1)[l15 * 2];
    float4 bb1 = ((const float4*)b1)[l15 * 2 + 1];
    float4 w0  = ((const float4*)W2)[l15 * 2];
    float4 w1  = ((const float4*)W2)[l15 * 2 + 1];
    float s = fmaxf(bflo(a.x) + bflo(b.x) + bb0.x, 0.f) * w0.x
            + fmaxf(bfhi(a.x) + bfhi(b.x) + bb0.y, 0.f) * w0.y
            + fmaxf(bflo(a.y) + bflo(b.y) + bb0.z, 0.f) * w0.z
            + fmaxf(bfhi(a.y) + bfhi(b.y) + bb0.w, 0.f) * w0.w
            + fmaxf(bflo(a.z) + bflo(b.z) + bb1.x, 0.f) * w1.x
            + fmaxf(bfhi(a.z) + bfhi(b.z) + bb1.y, 0.f) * w1.y
            + fmaxf(bflo(a.w) + bflo(b.w) + bb1.z, 0.f) * w1.z
            + fmaxf(bfhi(a.w) + bfhi(b.w) + bb1.w, 0.f) * w1.w;
    #pragma unroll
    for (int off = 8; off > 0; off >>= 1)
        s += __shfl_down(s, off, 16);
    if (l15 == 0) out[p] = s + b2[0];
}

// ===========================================================================
extern "C" void kernel_launch(void* const* d_in, const int* in_sizes, int n_in,
                              void* d_out, int out_size, void* d_ws, size_t ws_size,
                              hipStream_t stream) {
    const int*   ei_cf    = (const int*)d_in[2];
    const int*   ei_fc    = (const int*)d_in[3];
    const int*   eli      = (const int*)d_in[4];
    const float* can_emb  = (const float*)d_in[5];
    const float* flag_emb = (const float*)d_in[6];
    const float* Wl_cf    = (const float*)d_in[7];
    const float* bl_cf    = (const float*)d_in[8];
    const float* Wr_cf    = (const float*)d_in[9];
    const float* Wl_fc    = (const float*)d_in[10];
    const float* bl_fc    = (const float*)d_in[11];
    const float* Wr_fc    = (const float*)d_in[12];
    const float* W1       = (const float*)d_in[13];
    const float* b1       = (const float*)d_in[14];
    const float* W2       = (const float*)d_in[15];
    const float* b2       = (const float*)d_in[16];
    float* out = (float*)d_out;

    const int NCAN  = in_sizes[0];
    const int NFLAG = in_sizes[1];
    const int E     = in_sizes[2] / 2;
    const int L     = in_sizes[4] / 2;
    const int nTot  = NCAN + NFLAG;

    // type-pure bucketing: pad flag count to a 256 multiple
    const int NFB = (NFLAG + 255) >> 8;        // flag buckets
    const int NCB = (NCAN + 255) >> 8;         // can buckets
    const int Bq  = NFB + NCB;                 // total buckets
    const int NFP = NFB << 8;                  // padded flag id base for can

    // common bf16 buffers: out features (write-only) + emb copies
    ushort_t* aggc = (ushort_t*)d_ws;                         // NCAN*H
    ushort_t* aggf = aggc + (size_t)NCAN * H;                 // NFLAG*H
    ushort_t* embc = aggf + (size_t)NFLAG * H;                // NCAN*H
    ushort_t* embf = embc + (size_t)NCAN * H;                 // NFLAG*H
    char* tail = (char*)(embf + (size_t)NFLAG * H);
    size_t tail_off = (size_t)(tail - (char*)d_ws);

    int nbF = (NFLAG + 63) / 64, nbC = (NCAN + 63) / 64;
    int n4c = NCAN * H / 4, n4f = NFLAG * H / 4;
    int nbcvt = (n4c + n4f + 24576 + 255) / 256;

    // main tail: bcnt[MAXB] | bfront[MAXB] | part[2E] | wb
    size_t off_bcnt  = tail_off;
    size_t off_bfrnt = off_bcnt  + (size_t)MAXB * 4;
    size_t off_part  = off_bfrnt + (size_t)MAXB * 4;
    size_t off_wb    = off_part  + (size_t)2 * E * 4;
    size_t need_new  = off_wb + 98304 * 2;

    int* bcnt   = (int*)((char*)d_ws + off_bcnt);
    int* bfront = (int*)((char*)d_ws + off_bfrnt);

    if (ws_size >= need_new && Bq <= MAXB) {
        uint_t* part = (uint_t*)((char*)d_ws + off_part);
        ushort_t* wb = (ushort_t*)((char*)d_ws + off_wb);
        ushort_t* wb_wlcf = wb, *wb_wrcf = wb + 16384, *wb_wlfc = wb + 32768,
                 *wb_wrfc = wb + 49152, *wb_w1 = wb + 65536;

        int nbh = (2 * E + PCH - 1) / PCH;
        hipMemsetAsync(bcnt, 0, (size_t)2 * MAXB * 4, stream);   // bcnt + bfront
        bucket_hist_cvt_kernel<<<nbh + nbcvt, 256, 0, stream>>>(
            ei_cf, ei_fc, E, NFP, Bq, bcnt, nbh,
            can_emb, n4c, flag_emb, n4f, embc, embf,
            Wl_cf, Wr_cf, Wl_fc, Wr_fc, W1, wb);
        partition_kernel<<<nbh, 256, 0, stream>>>(ei_cf, ei_fc, E, NFP, Bq, bcnt, bfront, part);
        sage5_kernel<<<nbF + nbC, 256, 0, stream>>>(
            nbF, NFLAG, NCAN, NFB, bcnt, part,
            aggf, embf, aggc, embc,
            wb_wlcf, wb_wrcf, bl_cf, wb_wlfc, wb_wrfc, bl_fc, wb_w1);
    } else {
        // fallback: scattered bin2 CSR + incl->start fixup, then fused kernel
        int* offs   = (int*)((char*)d_ws + tail_off);           // nTot+1
        int* scanf_ = offs + (nTot + 1);           // NFLAG
        int* scanc_ = scanf_ + NFLAG;              // NCAN
        int* bins2  = scanc_ + NCAN;               // 2E
        int* bsums  = bins2 + 2 * E;               // 256
        ushort_t* wb = (ushort_t*)(bsums + 256);
        ushort_t* wb_wlcf = wb, *wb_wrcf = wb + 16384, *wb_wlfc = wb + 32768,
                 *wb_wrfc = wb + 49152, *wb_w1 = wb + 65536;

        bucket_hist_cvt_kernel<<<nbcvt, 256, 0, stream>>>(
            ei_cf, ei_fc, E, NFP, Bq, bcnt, 0,
            can_emb, n4c, flag_emb, n4f, embc, embf,
            Wl_cf, Wr_cf, Wl_fc, Wr_fc, W1, wb);
        hipMemsetAsync(scanf_, 0, ((size_t)NFLAG + NCAN) * 4, stream);
        int nb = (nTot + 1023) / 1024;
        hist2_kernel<<<(2 * E + 255) / 256, 256, 0, stream>>>(ei_cf, ei_fc, E, scanf_, scanc_);
        scan_blocksum_kernel<<<nb, 256, 0, stream>>>(scanf_, nTot, bsums);
        scan_write_kernel<<<nb, 256, 0, stream>>>(scanf_, nTot, bsums);
        bin2_kernel<<<(2 * E + 255) / 256, 256, 0, stream>>>(ei_cf, ei_fc, E, scanf_, scanc_, bins2);
        incl_to_start_kernel<<<(nTot + 255) / 256, 256, 0, stream>>>(scanf_, nTot, offs);
        sage4_kernel<<<nbF + nbC, 256, 0, stream>>>(
            nbF, NFLAG, NCAN, offs, bins2,
            aggf, embf, aggc, embc,
            wb_wlcf, wb_wrcf, bl_cf, wb_wlfc, wb_wrfc, bl_fc, wb_w1);
    }

    classify_kernel<<<(L + 15) / 16, 256, 0, stream>>>(
        eli, L, aggc, aggf, b1, W2, b2, out);
}

// Round 12
// 293.031 us; speedup vs baseline: 1.0911x; 1.0911x over previous
//
#include <hip/hip_runtime.h>
#include <hip/hip_bf16.h>

#define H 128
#define BSH 8              // 256 nodes per coarse bucket
#define MAXB 1024          // max buckets (nTot <= 262144)
#define PCH 4096           // edges per partition/hist block
#define PIT (PCH / 256)

typedef __attribute__((ext_vector_type(8))) short short8;
typedef __attribute__((ext_vector_type(4))) short short4v;
typedef __attribute__((ext_vector_type(4))) float floatx4;
typedef unsigned short ushort_t;
typedef unsigned int uint_t;

__device__ __forceinline__ short f2bf(float f) {
    __hip_bfloat16 h = __float2bfloat16(f);
    return *reinterpret_cast<short*>(&h);
}
__device__ __forceinline__ float bflo(uint_t u) { return __uint_as_float(u << 16); }
__device__ __forceinline__ float bfhi(uint_t u) { return __uint_as_float(u & 0xFFFF0000u); }
__device__ __forceinline__ uint_t pack_bf2(float x, float y) {
    return (uint_t)(ushort_t)f2bf(x) | ((uint_t)(ushort_t)f2bf(y) << 16);
}
__device__ __forceinline__ void acc8(float* acc, uint4 r) {
    acc[0] += bflo(r.x); acc[1] += bfhi(r.x);
    acc[2] += bflo(r.y); acc[3] += bfhi(r.y);
    acc[4] += bflo(r.z); acc[5] += bfhi(r.z);
    acc[6] += bflo(r.w); acc[7] += bfhi(r.w);
}

// ===========================================================================
// Coarse bucket histogram (LDS) + fused fp32->bf16 converts (emb + weights).
// ===========================================================================
__global__ __launch_bounds__(256)
void bucket_hist_cvt_kernel(const int* __restrict__ ei1, const int* __restrict__ ei2,
                            int E, int NF, int B, int* __restrict__ bcnt, int nbh,
                            const float* __restrict__ a, int n4a,
                            const float* __restrict__ b, int n4b,
                            ushort_t* __restrict__ da, ushort_t* __restrict__ db,
                            const float* __restrict__ Wl_cf, const float* __restrict__ Wr_cf,
                            const float* __restrict__ Wl_fc, const float* __restrict__ Wr_fc,
                            const float* __restrict__ W1, ushort_t* __restrict__ wb) {
    __shared__ int h[MAXB];
    int tid = threadIdx.x;
    if ((int)blockIdx.x < nbh) {
        for (int i = tid; i < B; i += 256) h[i] = 0;
        __syncthreads();
        int base = blockIdx.x * PCH;
        #pragma unroll 4
        for (int it = 0; it < PIT; ++it) {
            int t = base + it * 256 + tid;
            if (t < 2 * E) {
                int g = (t < E) ? ei1[E + t] : (ei2[E + t - E] + NF);
                atomicAdd(&h[g >> BSH], 1);
            }
        }
        __syncthreads();
        for (int i = tid; i < B; i += 256)
            if (h[i]) atomicAdd(&bcnt[i], h[i]);
        return;
    }
    // ---- cvt part ----
    int i = ((int)blockIdx.x - nbh) * 256 + tid;
    const float* src; ushort_t* dst; int k;
    if (i < n4a) { src = a; dst = da; k = i; }
    else if (i < n4a + n4b) { src = b; dst = db; k = i - n4a; }
    else {
        int idx = (i - n4a - n4b) * 4;
        if (idx >= 98304) return;
        int off;
        if      (idx < 16384) { src = Wl_cf; off = idx; }
        else if (idx < 32768) { src = Wr_cf; off = idx - 16384; }
        else if (idx < 49152) { src = Wl_fc; off = idx - 32768; }
        else if (idx < 65536) { src = Wr_fc; off = idx - 49152; }
        else                  { src = W1;    off = idx - 65536; }
        float4 v = *(const float4*)(src + off);
        short4v s;
        s[0] = f2bf(v.x); s[1] = f2bf(v.y); s[2] = f2bf(v.z); s[3] = f2bf(v.w);
        *(short4v*)(wb + idx) = s;
        return;
    }
    float4 v = ((const float4*)src)[k];
    short4v s;
    s[0] = f2bf(v.x); s[1] = f2bf(v.y); s[2] = f2bf(v.z); s[3] = f2bf(v.w);
    ((short4v*)dst)[k] = s;
}

// ===========================================================================
// Partition, single-pass-rank: pass 1 computes each edge's block-local rank
// via ONE LDS atomic and keeps (bucket, rank, payload) in registers
// (statically indexed via full unroll); pass 3 is pure stores.
// ===========================================================================
__global__ __launch_bounds__(256)
void partition_kernel(const int* __restrict__ ei1, const int* __restrict__ ei2,
                      int E, int NF, int B, const int* __restrict__ bcnt,
                      int* __restrict__ bfront, uint_t* __restrict__ part) {
    __shared__ int h[MAXB];
    __shared__ int basex[MAXB];
    __shared__ int sdata[256];
    int tid = threadIdx.x;
    // local exclusive scan of bcnt -> basex (global bucket bases)
    {
        int base4 = tid * 4;
        int v[4]; int s = 0;
        #pragma unroll
        for (int i = 0; i < 4; ++i) { int idx = base4 + i; v[i] = (idx < B) ? bcnt[idx] : 0; s += v[i]; }
        sdata[tid] = s;
        __syncthreads();
        for (int off = 1; off < 256; off <<= 1) {
            int t = (tid >= off) ? sdata[tid - off] : 0;
            __syncthreads();
            sdata[tid] += t;
            __syncthreads();
        }
        int excl = tid ? sdata[tid - 1] : 0;
        #pragma unroll
        for (int i = 0; i < 4; ++i) {
            int idx = base4 + i;
            if (idx < B) basex[idx] = excl;
            excl += v[i];
        }
    }
    for (int i = tid; i < B; i += 256) h[i] = 0;
    __syncthreads();

    int base = blockIdx.x * PCH;
    int pay[PIT]; int bkv[PIT]; int rv[PIT];
    #pragma unroll
    for (int it = 0; it < PIT; ++it) {
        int t = base + it * 256 + tid;
        bkv[it] = -1;
        if (t < 2 * E) {
            int g, s;
            if (t < E) { g = ei1[E + t]; s = ei1[t]; }
            else       { int e = t - E; g = ei2[E + e] + NF; s = ei2[e]; }
            int bk = g >> BSH;
            bkv[it] = bk;
            rv[it] = atomicAdd(&h[bk], 1);
            pay[it] = (int)(((uint_t)(g & 255) << 24) | (uint_t)s);
        }
    }
    __syncthreads();
    for (int i = tid; i < B; i += 256) {
        int c = h[i];
        if (c) basex[i] += atomicAdd(&bfront[i], c);   // reserve block's range
    }
    __syncthreads();
    #pragma unroll
    for (int it = 0; it < PIT; ++it) {
        if (bkv[it] >= 0)
            part[basex[bkv[it]] + rv[it]] = (uint_t)pay[it];
    }
}

// ===========================================================================
// Fine bin: one block per bucket; seg bounds from a local reduction over
// bcnt[0..b). LDS 256-hist + scan -> CSR start offsets + line-local bins.
// ===========================================================================
__global__ __launch_bounds__(256)
void fine_bin_kernel(const int* __restrict__ bcnt, int B, int nTot, int E2,
                     const uint_t* __restrict__ part,
                     int* __restrict__ offs, int* __restrict__ bins) {
    __shared__ int cnt[256];
    __shared__ int sdata[256];
    __shared__ int excl[256];
    int b = blockIdx.x;
    int tid = threadIdx.x;
    // seg0 = sum bcnt[0..b)
    {
        int partial = 0;
        for (int i = tid; i < b; i += 256) partial += bcnt[i];
        sdata[tid] = partial;
        __syncthreads();
        for (int off = 128; off > 0; off >>= 1) {
            if (tid < off) sdata[tid] += sdata[tid + off];
            __syncthreads();
        }
    }
    int seg0 = sdata[0];
    int seg1 = seg0 + bcnt[b];
    int gbase = b << BSH;
    __syncthreads();
    cnt[tid] = 0;
    __syncthreads();
    for (int k = seg0 + tid; k < seg1; k += 256)
        atomicAdd(&cnt[part[k] >> 24], 1);
    __syncthreads();
    sdata[tid] = cnt[tid];
    __syncthreads();
    for (int off = 1; off < 256; off <<= 1) {
        int t = (tid >= off) ? sdata[tid - off] : 0;
        __syncthreads();
        sdata[tid] += t;
        __syncthreads();
    }
    excl[tid] = tid ? sdata[tid - 1] : 0;
    int g = gbase + tid;
    if (g < nTot) offs[g] = seg0 + excl[tid];
    if (b == 0 && tid == 0) offs[nTot] = E2;
    cnt[tid] = 0;
    __syncthreads();
    for (int k = seg0 + tid; k < seg1; k += 256) {
        uint_t e = part[k];
        int l = (int)(e >> 24);
        int r = atomicAdd(&cnt[l], 1);
        bins[seg0 + excl[l] + r] = (int)(e & 0x00FFFFFFu);
    }
}

// ===========================================================================
// FUSED gather-mean + MFMA SAGE (sage4). 17.4 KB LDS -> ~8 blocks/CU.
//   phase G: 16-lane-group gather-mean, TWO rows per group interleaved.
//   MFMA Wl; restage self-emb rows; MFMA Wr; relu+bias epilogue; W1-part GEMM
// ===========================================================================
__global__ __launch_bounds__(256)
void sage4_kernel(int nbF, int NF, int NC,
                  const int* __restrict__ offs, const int* __restrict__ bins,
                  ushort_t* __restrict__ outf, const ushort_t* __restrict__ embf,
                  ushort_t* __restrict__ outc, const ushort_t* __restrict__ embc,
                  const ushort_t* __restrict__ wlf, const ushort_t* __restrict__ wrf,
                  const float* __restrict__ blf,
                  const ushort_t* __restrict__ wlc, const ushort_t* __restrict__ wrc,
                  const float* __restrict__ blc,
                  const ushort_t* __restrict__ W1) {
    __shared__ short A[64][136];              // 17408 B
    bool isF = (int)blockIdx.x < nbF;
    int nrows = isF ? NF : NC;
    int rbase = (isF ? blockIdx.x : blockIdx.x - nbF) * 64;
    ushort_t* io = isF ? outf : outc;         // write-only output
    const ushort_t* embS = isF ? embf : embc; // self rows
    const ushort_t* embN = isF ? embc : embf; // neighbor source rows
    const ushort_t* Wl = isF ? wlf : wlc;
    const ushort_t* Wr = isF ? wrf : wrc;
    const float* bl = isF ? blf : blc;
    int koff = isF ? 128 : 0;
    int gofs = isF ? 0 : NF;                  // global node-id base

    int tid = threadIdx.x;
    int lane = tid & 63;
    int wv = tid >> 6;
    int l15 = lane & 15;
    int quad = lane >> 4;
    int nb0 = 32 * wv + l15;

    float blv0 = bl[nb0];
    float blv1 = bl[nb0 + 16];

    // ---- phase G: gather means into A[:,0:128), 2 rows per group ----
    {
        const ushort_t* epN = embN + l15 * 8;
        #pragma unroll
        for (int half = 0; half < 2; ++half) {
            int r0 = wv * 16 + half * 8 + quad;   // row pair (r0, r0+4)
            int r1 = r0 + 4;
            int row0 = rbase + r0, row1 = rbase + r1;
            int st0 = 0, en0 = 0, st1 = 0, en1 = 0;
            if (row0 < nrows) { int g = gofs + row0; st0 = offs[g]; en0 = offs[g + 1]; }
            if (row1 < nrows) { int g = gofs + row1; st1 = offs[g]; en1 = offs[g + 1]; }
            int d0 = en0 - st0, d1 = en1 - st1;
            int n0 = d0 < 16 ? d0 : 16;
            int n1 = d1 < 16 ? d1 : 16;
            int pre0 = (l15 < n0) ? bins[st0 + l15] : 0;
            int pre1 = (l15 < n1) ? bins[st1 + l15] : 0;

            float a0[8], a1[8];
            #pragma unroll
            for (int t = 0; t < 8; ++t) { a0[t] = 0.f; a1[t] = 0.f; }

            int nmax = n0 > n1 ? n0 : n1;
            for (int k = 0; k < nmax; k += 2) {
                int s00 = __shfl(pre0, k,     16);
                int s01 = __shfl(pre0, k + 1, 16);
                int s10 = __shfl(pre1, k,     16);
                int s11 = __shfl(pre1, k + 1, 16);
                bool b00 = k < n0, b01 = (k + 1) < n0;
                bool b10 = k < n1, b11 = (k + 1) < n1;
                uint4 q00, q01, q10, q11;
                if (b00) q00 = *(const uint4*)(epN + (size_t)s00 * H);
                if (b10) q10 = *(const uint4*)(epN + (size_t)s10 * H);
                if (b01) q01 = *(const uint4*)(epN + (size_t)s01 * H);
                if (b11) q11 = *(const uint4*)(epN + (size_t)s11 * H);
                if (b00) acc8(a0, q00);
                if (b10) acc8(a1, q10);
                if (b01) acc8(a0, q01);
                if (b11) acc8(a1, q11);
            }
            for (int kk = st0 + 16; kk < en0; ++kk) {
                int s = bins[kk];
                uint4 rr = *(const uint4*)(epN + (size_t)s * H);
                acc8(a0, rr);
            }
            for (int kk = st1 + 16; kk < en1; ++kk) {
                int s = bins[kk];
                uint4 rr = *(const uint4*)(epN + (size_t)s * H);
                acc8(a1, rr);
            }

            float inv0 = 1.0f / fmaxf((float)d0, 1.0f);
            float inv1 = 1.0f / fmaxf((float)d1, 1.0f);
            uint4 o0, o1;
            o0.x = pack_bf2(a0[0] * inv0, a0[1] * inv0);
            o0.y = pack_bf2(a0[2] * inv0, a0[3] * inv0);
            o0.z = pack_bf2(a0[4] * inv0, a0[5] * inv0);
            o0.w = pack_bf2(a0[6] * inv0, a0[7] * inv0);
            o1.x = pack_bf2(a1[0] * inv1, a1[1] * inv1);
            o1.y = pack_bf2(a1[2] * inv1, a1[3] * inv1);
            o1.z = pack_bf2(a1[4] * inv1, a1[5] * inv1);
            o1.w = pack_bf2(a1[6] * inv1, a1[7] * inv1);
            *(uint4*)&A[r0][l15 * 8] = o0;
            *(uint4*)&A[r1][l15 * 8] = o1;
        }
    }

    floatx4 acc[4][2];
    #pragma unroll
    for (int i = 0; i < 4; ++i)
        #pragma unroll
        for (int j = 0; j < 2; ++j)
            acc[i][j] = (floatx4){0.f, 0.f, 0.f, 0.f};

    __syncthreads();
    #pragma unroll
    for (int ks = 0; ks < 4; ++ks) {
        int kb = ks * 32 + quad * 8;
        short8 b0 = *(const short8*)(Wl + (size_t)nb0 * H + kb);
        short8 b1 = *(const short8*)(Wl + (size_t)(nb0 + 16) * H + kb);
        #pragma unroll
        for (int mt = 0; mt < 4; ++mt) {
            short8 a = *(const short8*)&A[16 * mt + l15][kb];
            acc[mt][0] = __builtin_amdgcn_mfma_f32_16x16x32_bf16(a, b0, acc[mt][0], 0, 0, 0);
            acc[mt][1] = __builtin_amdgcn_mfma_f32_16x16x32_bf16(a, b1, acc[mt][1], 0, 0, 0);
        }
    }
    __syncthreads();

    // ---- stage self-emb rows into same buffer ----
    #pragma unroll
    for (int j = 0; j < 4; ++j) {
        int idx = tid + 256 * j;
        int r = idx >> 4, c = idx & 15;
        int row = rbase + r;
        uint4 v = (uint4){0u, 0u, 0u, 0u};
        if (row < nrows) v = *(const uint4*)(embS + (size_t)row * H + c * 8);
        *(uint4*)&A[r][c * 8] = v;
    }
    __syncthreads();
    #pragma unroll
    for (int ks = 0; ks < 4; ++ks) {
        int kb = ks * 32 + quad * 8;
        short8 b0 = *(const short8*)(Wr + (size_t)nb0 * H + kb);
        short8 b1 = *(const short8*)(Wr + (size_t)(nb0 + 16) * H + kb);
        #pragma unroll
        for (int mt = 0; mt < 4; ++mt) {
            short8 a = *(const short8*)&A[16 * mt + l15][kb];
            acc[mt][0] = __builtin_amdgcn_mfma_f32_16x16x32_bf16(a, b0, acc[mt][0], 0, 0, 0);
            acc[mt][1] = __builtin_amdgcn_mfma_f32_16x16x32_bf16(a, b1, acc[mt][1], 0, 0, 0);
        }
    }
    __syncthreads();

    // ---- epilogue: relu+bias -> A[64][0:128) ----
    #pragma unroll
    for (int mt = 0; mt < 4; ++mt)
        #pragma unroll
        for (int nt = 0; nt < 2; ++nt) {
            float blv = nt ? blv1 : blv0;
            int colw = nb0 + 16 * nt;
            #pragma unroll
            for (int rg = 0; rg < 4; ++rg) {
                int row = 16 * mt + quad * 4 + rg;
                A[row][colw] = f2bf(fmaxf(acc[mt][nt][rg] + blv, 0.0f));
                acc[mt][nt][rg] = 0.0f;
            }
        }
    __syncthreads();

    // ---- W1-part GEMM ----
    const ushort_t* W1p = W1 + koff;
    #pragma unroll
    for (int ks = 0; ks < 4; ++ks) {
        int kb = ks * 32 + quad * 8;
        short8 b0 = *(const short8*)(W1p + (size_t)nb0 * 256 + kb);
        short8 b1 = *(const short8*)(W1p + (size_t)(nb0 + 16) * 256 + kb);
        #pragma unroll
        for (int mt = 0; mt < 4; ++mt) {
            short8 a = *(const short8*)&A[16 * mt + l15][kb];
            acc[mt][0] = __builtin_amdgcn_mfma_f32_16x16x32_bf16(a, b0, acc[mt][0], 0, 0, 0);
            acc[mt][1] = __builtin_amdgcn_mfma_f32_16x16x32_bf16(a, b1, acc[mt][1], 0, 0, 0);
        }
    }

    #pragma unroll
    for (int mt = 0; mt < 4; ++mt)
        #pragma unroll
        for (int rg = 0; rg < 4; ++rg) {
            int row = rbase + 16 * mt + quad * 4 + rg;
            if (row < nrows) {
                io[(size_t)row * H + nb0]      = (ushort_t)f2bf(acc[mt][0][rg]);
                io[(size_t)row * H + nb0 + 16] = (ushort_t)f2bf(acc[mt][1][rg]);
            }
        }
}

// ===========================================================================
// Fallback CSR kernels (scattered bin2 path) — only if ws too small.
// ===========================================================================
__global__ __launch_bounds__(256)
void hist2_kernel(const int* __restrict__ ei1, const int* __restrict__ ei2, int E,
                  int* __restrict__ deg1, int* __restrict__ deg2) {
    int t = blockIdx.x * 256 + threadIdx.x;
    if (t < E) atomicAdd(&deg1[ei1[E + t]], 1);
    else if (t < 2 * E) { int e = t - E; atomicAdd(&deg2[ei2[E + e]], 1); }
}

__global__ __launch_bounds__(256)
void scan_blocksum_kernel(const int* __restrict__ deg, int n, int* __restrict__ bsums) {
    __shared__ int sdata[256];
    int tid = threadIdx.x;
    int base = blockIdx.x * 1024 + tid * 4;
    int v = 0;
    #pragma unroll
    for (int i = 0; i < 4; ++i) { int idx = base + i; if (idx < n) v += deg[idx]; }
    sdata[tid] = v;
    __syncthreads();
    for (int off = 128; off > 0; off >>= 1) {
        if (tid < off) sdata[tid] += sdata[tid + off];
        __syncthreads();
    }
    if (tid == 0) bsums[blockIdx.x] = sdata[0];
}

__global__ __launch_bounds__(256)
void scan_write_kernel(int* __restrict__ data, int n, const int* __restrict__ bsums) {
    __shared__ int sdata[256];
    __shared__ int boff;
    int tid = threadIdx.x;
    if (tid < 64) {
        int acc = 0;
        for (int i = tid; i < (int)blockIdx.x; i += 64) acc += bsums[i];
        #pragma unroll
        for (int off = 32; off > 0; off >>= 1) acc += __shfl_xor(acc, off, 64);
        if (tid == 0) boff = acc;
    }
    int base = blockIdx.x * 1024 + tid * 4;
    int v[4]; int s = 0;
    #pragma unroll
    for (int i = 0; i < 4; ++i) { int idx = base + i; v[i] = (idx < n) ? data[idx] : 0; s += v[i]; }
    sdata[tid] = s;
    __syncthreads();
    for (int off = 1; off < 256; off <<= 1) {
        int t = (tid >= off) ? sdata[tid - off] : 0;
        __syncthreads();
        sdata[tid] += t;
        __syncthreads();
    }
    int excl = (tid == 0 ? 0 : sdata[tid - 1]) + boff;
    #pragma unroll
    for (int i = 0; i < 4; ++i) {
        int idx = base + i;
        if (idx < n) data[idx] = excl;
        excl += v[i];
    }
}

__global__ __launch_bounds__(256)
void incl_to_start_kernel(const int* __restrict__ incl, int nTot, int* __restrict__ offs) {
    int g = blockIdx.x * 256 + threadIdx.x;
    if (g < nTot) offs[g + 1] = incl[g];
    if (g == 0) offs[0] = 0;
}

__global__ __launch_bounds__(256)
void bin2_kernel(const int* __restrict__ ei1, const int* __restrict__ ei2, int E,
                 int* __restrict__ offs1, int* __restrict__ offs2,
                 int* __restrict__ bins) {
    int t = blockIdx.x * 256 + threadIdx.x;
    if (t < E) {
        int pos = atomicAdd(&offs1[ei1[E + t]], 1);
        bins[pos] = ei1[t];
    } else if (t < 2 * E) {
        int e = t - E;
        int pos = atomicAdd(&offs2[ei2[E + e]], 1);
        bins[pos] = ei2[e];
    }
}

// ===========================================================================
// Classifier: 16 lanes per group, TWO pairs per group interleaved (all four
// row-loads issued before either accumulation; b1/W2 broadcast reused).
// Same per-pair arithmetic and reduction order as before.
// ===========================================================================
__global__ __launch_bounds__(256)
void classify_kernel(const int* __restrict__ eli, int L,
                     const ushort_t* __restrict__ u_can,
                     const ushort_t* __restrict__ u_flag,
                     const float* __restrict__ b1,
                     const float* __restrict__ W2,
                     const float* __restrict__ b2,
                     float* __restrict__ out) {
    int tid = threadIdx.x;
    int grp = tid >> 4;
    int l15 = tid & 15;
    int p0 = blockIdx.x * 32 + grp * 2;
    int p1 = p0 + 1;
    if (p0 >= L) return;
    bool v1 = p1 < L;
    int i0 = eli[p0];
    int j0 = eli[L + p0];
    int i1 = v1 ? eli[p1] : i0;
    int j1 = v1 ? eli[L + p1] : j0;
    uint4 a0 = ((const uint4*)(u_can  + (size_t)i0 * H))[l15];
    uint4 c0 = ((const uint4*)(u_flag + (size_t)j0 * H))[l15];
    uint4 a1 = ((const uint4*)(u_can  + (size_t)i1 * H))[l15];
    uint4 c1 = ((const uint4*)(u_flag + (size_t)j1 * H))[l15];
    float4 bb0 = ((const float4*)b1)[l15 * 2];
    float4 bb1 = ((const float4*)b1)[l15 * 2 + 1];
    float4 w0  = ((const float4*)W2)[l15 * 2];
    float4 w1  = ((const float4*)W2)[l15 * 2 + 1];
    float s0 = fmaxf(bflo(a0.x) + bflo(c0.x) + bb0.x, 0.f) * w0.x
             + fmaxf(bfhi(a0.x) + bfhi(c0.x) + bb0.y, 0.f) * w0.y
             + fmaxf(bflo(a0.y) + bflo(c0.y) + bb0.z, 0.f) * w0.z
             + fmaxf(bfhi(a0.y) + bfhi(c0.y) + bb0.w, 0.f) * w0.w
             + fmaxf(bflo(a0.z) + bflo(c0.z) + bb1.x, 0.f) * w1.x
             + fmaxf(bfhi(a0.z) + bfhi(c0.z) + bb1.y, 0.f) * w1.y
             + fmaxf(bflo(a0.w) + bflo(c0.w) + bb1.z, 0.f) * w1.z
             + fmaxf(bfhi(a0.w) + bfhi(c0.w) + bb1.w, 0.f) * w1.w;
    float s1 = fmaxf(bflo(a1.x) + bflo(c1.x) + bb0.x, 0.f) * w0.x
             + fmaxf(bfhi(a1.x) + bfhi(c1.x) + bb0.y, 0.f) * w0.y
             + fmaxf(bflo(a1.y) + bflo(c1.y) + bb0.z, 0.f) * w0.z
             + fmaxf(bfhi(a1.y) + bfhi(c1.y) + bb0.w, 0.f) * w0.w
             + fmaxf(bflo(a1.z) + bflo(c1.z) + bb1.x, 0.f) * w1.x
             + fmaxf(bfhi(a1.z) + bfhi(c1.z) + bb1.y, 0.f) * w1.y
             + fmaxf(bflo(a1.w) + bflo(c1.w) + bb1.z, 0.f) * w1.z
             + fmaxf(bfhi(a1.w) + bfhi(c1.w) + bb1.w, 0.f) * w1.w;
    #pragma unroll
    for (int off = 8; off > 0; off >>= 1) {
        s0 += __shfl_down(s0, off, 16);
        s1 += __shfl_down(s1, off, 16);
    }
    if (l15 == 0) {
        out[p0] = s0 + b2[0];
        if (v1) out[p1] = s1 + b2[0];
    }
}

// ===========================================================================
extern "C" void kernel_launch(void* const* d_in, const int* in_sizes, int n_in,
                              void* d_out, int out_size, void* d_ws, size_t ws_size,
                              hipStream_t stream) {
    const int*   ei_cf    = (const int*)d_in[2];
    const int*   ei_fc    = (const int*)d_in[3];
    const int*   eli      = (const int*)d_in[4];
    const float* can_emb  = (const float*)d_in[5];
    const float* flag_emb = (const float*)d_in[6];
    const float* Wl_cf    = (const float*)d_in[7];
    const float* bl_cf    = (const float*)d_in[8];
    const float* Wr_cf    = (const float*)d_in[9];
    const float* Wl_fc    = (const float*)d_in[10];
    const float* bl_fc    = (const float*)d_in[11];
    const float* Wr_fc    = (const float*)d_in[12];
    const float* W1       = (const float*)d_in[13];
    const float* b1       = (const float*)d_in[14];
    const float* W2       = (const float*)d_in[15];
    const float* b2       = (const float*)d_in[16];
    float* out = (float*)d_out;

    const int NCAN  = in_sizes[0];
    const int NFLAG = in_sizes[1];
    const int E     = in_sizes[2] / 2;
    const int L     = in_sizes[4] / 2;
    const int nTot  = NCAN + NFLAG;
    const int B     = (nTot + 255) >> BSH;

    // common bf16 buffers: out features (write-only) + emb copies
    ushort_t* aggc = (ushort_t*)d_ws;                         // NCAN*H
    ushort_t* aggf = aggc + (size_t)NCAN * H;                 // NFLAG*H
    ushort_t* embc = aggf + (size_t)NFLAG * H;                // NCAN*H
    ushort_t* embf = embc + (size_t)NCAN * H;                 // NFLAG*H
    char* tail = (char*)(embf + (size_t)NFLAG * H);
    size_t tail_off = (size_t)(tail - (char*)d_ws);

    int nbF = (NFLAG + 63) / 64, nbC = (NCAN + 63) / 64;
    int n4c = NCAN * H / 4, n4f = NFLAG * H / 4;
    int nbcvt = (n4c + n4f + 24576 + 255) / 256;

    // tail: offs[nTot+1] | bcnt[MAXB] | bfront[MAXB] (contig, one memset) |
    //       bins[2E] | part[2E] (uint, 4B) | wb
    size_t off_offs  = tail_off;
    size_t off_bcnt  = off_offs  + (size_t)(nTot + 1) * 4;
    size_t off_bfrnt = off_bcnt  + (size_t)MAXB * 4;
    size_t off_bins  = off_bfrnt + (size_t)MAXB * 4;
    size_t off_part  = off_bins  + (size_t)2 * E * 4;
    size_t off_wb    = off_part  + (size_t)2 * E * 4;
    size_t need_new  = off_wb + 98304 * 2;

    int* offs   = (int*)((char*)d_ws + off_offs);
    int* bcnt   = (int*)((char*)d_ws + off_bcnt);
    int* bfront = (int*)((char*)d_ws + off_bfrnt);
    int* bins   = (int*)((char*)d_ws + off_bins);

    if (ws_size >= need_new && B <= MAXB) {
        uint_t* part = (uint_t*)((char*)d_ws + off_part);
        ushort_t* wb = (ushort_t*)((char*)d_ws + off_wb);
        ushort_t* wb_wlcf = wb, *wb_wrcf = wb + 16384, *wb_wlfc = wb + 32768,
                 *wb_wrfc = wb + 49152, *wb_w1 = wb + 65536;

        int nbh = (2 * E + PCH - 1) / PCH;
        hipMemsetAsync(bcnt, 0, (size_t)2 * MAXB * 4, stream);   // bcnt + bfront
        bucket_hist_cvt_kernel<<<nbh + nbcvt, 256, 0, stream>>>(
            ei_cf, ei_fc, E, NFLAG, B, bcnt, nbh,
            can_emb, n4c, flag_emb, n4f, embc, embf,
            Wl_cf, Wr_cf, Wl_fc, Wr_fc, W1, wb);
        partition_kernel<<<nbh, 256, 0, stream>>>(ei_cf, ei_fc, E, NFLAG, B, bcnt, bfront, part);
        fine_bin_kernel<<<B, 256, 0, stream>>>(bcnt, B, nTot, 2 * E, part, offs, bins);
        sage4_kernel<<<nbF + nbC, 256, 0, stream>>>(
            nbF, NFLAG, NCAN, offs, bins,
            aggf, embf, aggc, embc,
            wb_wlcf, wb_wrcf, bl_cf, wb_wlfc, wb_wrfc, bl_fc, wb_w1);
    } else {
        // fallback: scattered bin2 CSR + incl->start fixup, then fused kernel
        int* scanf_ = bins;                        // NFLAG
        int* scanc_ = scanf_ + NFLAG;              // NCAN
        int* bins2  = scanc_ + NCAN;               // 2E
        int* bsums  = bins2 + 2 * E;               // 256
        ushort_t* wb = (ushort_t*)(bsums + 256);
        ushort_t* wb_wlcf = wb, *wb_wrcf = wb + 16384, *wb_wlfc = wb + 32768,
                 *wb_wrfc = wb + 49152, *wb_w1 = wb + 65536;

        bucket_hist_cvt_kernel<<<nbcvt, 256, 0, stream>>>(
            ei_cf, ei_fc, E, NFLAG, B, bcnt, 0,
            can_emb, n4c, flag_emb, n4f, embc, embf,
            Wl_cf, Wr_cf, Wl_fc, Wr_fc, W1, wb);
        hipMemsetAsync(scanf_, 0, ((size_t)NFLAG + NCAN) * 4, stream);
        int nb = (nTot + 1023) / 1024;
        hist2_kernel<<<(2 * E + 255) / 256, 256, 0, stream>>>(ei_cf, ei_fc, E, scanf_, scanc_);
        scan_blocksum_kernel<<<nb, 256, 0, stream>>>(scanf_, nTot, bsums);
        scan_write_kernel<<<nb, 256, 0, stream>>>(scanf_, nTot, bsums);
        bin2_kernel<<<(2 * E + 255) / 256, 256, 0, stream>>>(ei_cf, ei_fc, E, scanf_, scanc_, bins2);
        incl_to_start_kernel<<<(nTot + 255) / 256, 256, 0, stream>>>(scanf_, nTot, offs);
        sage4_kernel<<<nbF + nbC, 256, 0, stream>>>(
            nbF, NFLAG, NCAN, offs, bins2,
            aggf, embf, aggc, embc,
            wb_wlcf, wb_wrcf, bl_cf, wb_wlfc, wb_wrfc, bl_fc, wb_w1);
    }

    classify_kernel<<<(L + 31) / 32, 256, 0, stream>>>(
        eli, L, aggc, aggf, b1, W2, b2, out);
}